// Round 9
// baseline (3739.385 us; speedup 1.0000x reference)
//
#include <hip/hip_runtime.h>
#include <hip/hip_bf16.h>
#include <math.h>

// ---------------------------------------------------------------------------
// GPT-style transformer forward. Round 9: round-6 base + depth-2 prefetch.
// L=4, H=12, HD=64, D=768, V=50257, B=1, T=2048
// Rounds 7/8 (gload_lds, shuffled pool, direct-reg A) both REGRESSED; revert
// to round-6 structure (best: 2724us, VGPR 76, occ 33%).
// Round-6 diagnosis: k_mm load->use distance = one MFMA phase (~150cy) vs
// 200-900cy mem latency; MfmaUtil pinned at 13% (= measured 332 TF on LMH).
// Single change: two named staging-register sets (rgA/rgB), 2-step-unrolled
// K-loop; loads for tile t+2 issue at top of step t, consumed a full K-step
// later (~600-800cy coverage). All else identical to round 6.
// ---------------------------------------------------------------------------

typedef __attribute__((ext_vector_type(8))) short bf16x8;
typedef __attribute__((ext_vector_type(4))) float f32x4;
typedef unsigned short u16;

// bf16 weight-pool layout (elems per layer): [qkv 2304x768][o 768x768]
// [w1 3072x768][w2 768x3072]   (linear row-major, round-6 layout)
constexpr int OSZ   = 589824;        // 768*768
constexpr int QKVSZ = 3 * OSZ;       // 1769472
constexpr int W1SZ  = 2359296;       // 3072*768
constexpr int PER_L = QKVSZ + OSZ + W1SZ + W1SZ;  // 7077888

__device__ __forceinline__ u16 f2bf(float f) {
  unsigned u = __float_as_uint(f);
  u += 0x7FFFu + ((u >> 16) & 1u);
  return (u16)(u >> 16);
}

__device__ __forceinline__ float gelu_exact(float v) {
  return 0.5f * v * (1.0f + erff(v * 0.70710678118654752f));
}

// Bijective XCD swizzle (m204): contiguous logical chunk per XCD.
__device__ __forceinline__ int xcd_swizzle(int orig, int nwg) {
  int xcd = orig & 7, lid = orig >> 3;
  int q8 = nwg >> 3, r8 = nwg & 7;
  return (xcd < r8 ? xcd * (q8 + 1) : r8 * (q8 + 1) + (xcd - r8) * q8) + lid;
}

__global__ __launch_bounds__(256) void k_embed(const int* __restrict__ ids,
                                               const float* __restrict__ emb,
                                               float* __restrict__ x,
                                               int T, int D) {
  int t = blockIdx.x;
  int id = ids[t];
  float neg_log = -logf(10000.0f) / (float)D;
  for (int d = threadIdx.x; d < D; d += 256) {
    float freq = expf((float)(d & ~1) * neg_log);
    float ang = (float)t * freq;
    float pe = (d & 1) ? cosf(ang) : sinf(ang);
    x[(size_t)t * D + d] = emb[(size_t)id * D + d] + pe;
  }
}

// LayerNorm, bf16 output (same rounding the consumer GEMM applied before).
__global__ __launch_bounds__(256) void k_layernorm(const float* __restrict__ x,
                                                   const float* __restrict__ g,
                                                   const float* __restrict__ b,
                                                   u16* __restrict__ y,
                                                   int D) {
  int t = blockIdx.x;
  const float* xr = x + (size_t)t * D;
  __shared__ float red[256];
  float s = 0.f;
  for (int d = threadIdx.x; d < D; d += 256) s += xr[d];
  red[threadIdx.x] = s;
  __syncthreads();
  for (int st = 128; st > 0; st >>= 1) {
    if (threadIdx.x < st) red[threadIdx.x] += red[threadIdx.x + st];
    __syncthreads();
  }
  float mean = red[0] / (float)D;
  __syncthreads();
  float s2 = 0.f;
  for (int d = threadIdx.x; d < D; d += 256) {
    float u = xr[d] - mean;
    s2 += u * u;
  }
  red[threadIdx.x] = s2;
  __syncthreads();
  for (int st = 128; st > 0; st >>= 1) {
    if (threadIdx.x < st) red[threadIdx.x] += red[threadIdx.x + st];
    __syncthreads();
  }
  float rstd = rsqrtf(red[0] / (float)D + 1e-5f);
  u16* yr = y + (size_t)t * D;
  for (int d = threadIdx.x; d < D; d += 256)
    yr[d] = f2bf((xr[d] - mean) * rstd * g[d] + b[d]);
}

// One-time weight cast: fp32 inputs -> bf16 pool (linear). 8 elems/thr.
__global__ __launch_bounds__(256) void k_castw(const float* __restrict__ Wq,
                                               const float* __restrict__ Wk,
                                               const float* __restrict__ Wv,
                                               const float* __restrict__ Wo,
                                               const float* __restrict__ W1,
                                               const float* __restrict__ W2,
                                               u16* __restrict__ pool) {
  unsigned i8 = (blockIdx.x * 256u + threadIdx.x) * 8u;
  unsigned l = i8 / (unsigned)PER_L;
  unsigned off = i8 - l * (unsigned)PER_L;
  const float* src;
  if (off < (unsigned)QKVSZ) {
    unsigned w = off / (unsigned)OSZ;
    unsigned o = off - w * (unsigned)OSZ;
    src = (w == 0 ? Wq : (w == 1 ? Wk : Wv)) + (size_t)l * OSZ + o;
  } else if (off < (unsigned)(QKVSZ + OSZ)) {
    src = Wo + (size_t)l * OSZ + (off - QKVSZ);
  } else if (off < (unsigned)(QKVSZ + OSZ + W1SZ)) {
    src = W1 + (size_t)l * W1SZ + (off - (QKVSZ + OSZ));
  } else {
    src = W2 + (size_t)l * W1SZ + (off - (QKVSZ + OSZ + W1SZ));
  }
  float4 a = *(const float4*)src;
  float4 b = *(const float4*)(src + 4);
  union { bf16x8 v; u16 u[8]; } r;
  r.u[0] = f2bf(a.x); r.u[1] = f2bf(a.y); r.u[2] = f2bf(a.z); r.u[3] = f2bf(a.w);
  r.u[4] = f2bf(b.x); r.u[5] = f2bf(b.y); r.u[6] = f2bf(b.z); r.u[7] = f2bf(b.w);
  *(bf16x8*)(pool + i8) = r.v;
}

// Concatenated QKV bias.
__global__ __launch_bounds__(256) void k_castb(const float* __restrict__ bq,
                                               const float* __restrict__ bk,
                                               const float* __restrict__ bv,
                                               float* __restrict__ bqkv) {
  for (int i = threadIdx.x; i < 4 * 2304; i += 256) {
    int l = i / 2304, c = i - l * 2304;
    int w = c / 768, cc = c - w * 768;
    bqkv[i] = (w == 0 ? bq : (w == 1 ? bk : bv))[l * 768 + cc];
  }
}

// ---------------------------------------------------------------------------
// k_mm_bf: C[M,N] = A[M,K](bf16) @ B[N,K](bf16)^T + bias[N]
// mode 0: bias, fp32 C; mode 1: bias+res, fp32 C; mode 2: gelu, bf16 C.
// M%128==0, N%128==0, K%64==0, NK=K/32 even>=4 (all layer GEMMs qualify).
// 128x128 tile, BK=32, 4 waves (64x64 quadrant), mfma 16x16x32 bf16.
// Round-6 mat-split reg staging (threads 0-127: A rows, 128-255: B rows;
// 4 rows x 16B each), padded planes. NEW: depth-2 prefetch -- rgA/rgB
// ping-pong, loads for tile t+2 issued at top of step t.
// ---------------------------------------------------------------------------
__global__ __launch_bounds__(256) void k_mm_bf(const u16* __restrict__ A,
                                               const u16* __restrict__ B,
                                               const float* __restrict__ bias,
                                               const float* __restrict__ res,
                                               void* __restrict__ Cv,
                                               int M, int N, int K, int mode) {
  constexpr int PLANE = 2080;      // 128 rows * 16 B + 32 pad
  constexpr int MATS  = 4 * PLANE;
  constexpr int BUFSZ = 2 * MATS;  // A+B per buffer (16640 B)
  __shared__ alignas(16) unsigned char smem[2 * BUFSZ];

  const int nbx = N >> 7;
  const int nby = M >> 7;
  const int swz = xcd_swizzle(blockIdx.x, nbx * nby);
  const int nb = swz / nby;        // n panel major
  const int mb = swz - nb * nby;   // m fastest
  const int m0 = mb << 7, n0 = nb << 7;

  const int tid = threadIdx.x;
  const int lane = tid & 63;
  const int wid = tid >> 6;
  const int wr = wid >> 1, wc = wid & 1;

  const int mat = tid >> 7;        // 0: stage A, 1: stage B
  const int ts = tid & 127;
  const int kslot = ts & 3;
  const int r0 = ts >> 2;          // rows r0 + {0,32,64,96}
  const u16* gbase = mat ? B : A;
  const int gr0 = (mat ? n0 : m0) + r0;
  unsigned char* wb0 = smem + mat * MATS + kslot * PLANE;

  const int lr = lane & 15, lk = lane >> 4;
  const int ardo = lk * PLANE + (wr * 64 + lr) * 16;
  const int brdo = MATS + lk * PLANE + (wc * 64 + lr) * 16;

  f32x4 acc[4][4] = {};
  bf16x8 rgA[4], rgB[4];
  const int NK = K >> 5;

  auto LOADT = [&](bf16x8 (&rg)[4], int kt) {
    const int ko = (kt << 5) + (kslot << 3);
#pragma unroll
    for (int i = 0; i < 4; ++i)
      rg[i] = *(const bf16x8*)(gbase + (size_t)(gr0 + (i << 5)) * K + ko);
  };
  auto STORET = [&](const bf16x8 (&rg)[4], int buf) {
    unsigned char* wb = wb0 + buf * BUFSZ;
#pragma unroll
    for (int i = 0; i < 4; ++i)
      *(bf16x8*)(wb + (r0 + (i << 5)) * 16) = rg[i];
  };
  auto COMPUTE = [&](int buf) {
    const unsigned char* base = smem + buf * BUFSZ;
    bf16x8 af[4], bfr[4];
#pragma unroll
    for (int f = 0; f < 4; ++f) {
      af[f]  = *(const bf16x8*)(base + ardo + f * 256);
      bfr[f] = *(const bf16x8*)(base + brdo + f * 256);
    }
#pragma unroll
    for (int fm = 0; fm < 4; ++fm)
#pragma unroll
      for (int fn = 0; fn < 4; ++fn)
        acc[fm][fn] = __builtin_amdgcn_mfma_f32_16x16x32_bf16(
            af[fm], bfr[fn], acc[fm][fn], 0, 0, 0);
  };

  // prologue: tile0 -> buf0; tile1 in flight in rgB
  LOADT(rgA, 0);
  STORET(rgA, 0);
  LOADT(rgB, 1);
  __syncthreads();

  for (int kt = 0; kt < NK; kt += 2) {
    // even step: compute tile kt (buf0); rgB holds tile kt+1 (issued 1 step ago)
    if (kt + 2 < NK) LOADT(rgA, kt + 2);
    COMPUTE(0);
    STORET(rgB, 1);            // vmcnt wait for rgB: ~1 full step covered
    __syncthreads();
    // odd step: compute tile kt+1 (buf1); rgA holds tile kt+2
    if (kt + 3 < NK) LOADT(rgB, kt + 3);
    COMPUTE(1);
    if (kt + 2 < NK) {
      STORET(rgA, 0);
      __syncthreads();
    }
  }

  // epilogue: C/D layout col = lane&15, row = (lane>>4)*4 + reg
  const int orow0 = m0 + wr * 64 + (lk << 2);
  const int ocol0 = n0 + wc * 64 + lr;
  if (mode == 2) {
    u16* C = (u16*)Cv;
#pragma unroll
    for (int fn = 0; fn < 4; ++fn) {
      int col = ocol0 + fn * 16;
      float bv = bias[col];
#pragma unroll
      for (int fm = 0; fm < 4; ++fm)
#pragma unroll
        for (int j = 0; j < 4; ++j) {
          int row = orow0 + fm * 16 + j;
          C[(size_t)row * N + col] = f2bf(gelu_exact(acc[fm][fn][j] + bv));
        }
    }
  } else {
    float* C = (float*)Cv;
#pragma unroll
    for (int fn = 0; fn < 4; ++fn) {
      int col = ocol0 + fn * 16;
      float bv = bias[col];
#pragma unroll
      for (int fm = 0; fm < 4; ++fm)
#pragma unroll
        for (int j = 0; j < 4; ++j) {
          int row = orow0 + fm * 16 + j;
          float vvv = acc[fm][fn][j] + bv;
          if (mode == 1) vvv += res[(size_t)row * N + col];
          C[(size_t)row * N + col] = vvv;
        }
    }
  }
}

// ---------------------------------------------------------------------------
// k_mm_lmh: LM head. C[M,N] = A[M,K](bf16) @ B[N,K](fp32->bf16)^T + bias.
// Round-6 structure (mat-split: A threads 16B/row raw, B threads 32B/row
// fp32 converted in STORE), + depth-2 prefetch (rgA_/rgB_ float4[4][2]).
// B rows clamped to N-1 (garbage cols never stored: epilogue guards col<N).
// ---------------------------------------------------------------------------
__global__ __launch_bounds__(256) void k_mm_lmh(const u16* __restrict__ A,
                                                const float* __restrict__ B,
                                                const float* __restrict__ bias,
                                                float* __restrict__ C,
                                                int M, int N, int K) {
  constexpr int PLANE = 2080;
  constexpr int MATS  = 4 * PLANE;
  constexpr int BUFSZ = 2 * MATS;
  __shared__ alignas(16) unsigned char smem[2 * BUFSZ];

  const int nbx = (N + 127) >> 7;
  const int nby = M >> 7;
  const int swz = xcd_swizzle(blockIdx.x, nbx * nby);
  const int nb = swz / nby;
  const int mb = swz - nb * nby;
  const int m0 = mb << 7, n0 = nb << 7;

  const int tid = threadIdx.x;
  const int lane = tid & 63;
  const int wid = tid >> 6;
  const int wr = wid >> 1, wc = wid & 1;

  const int mat = tid >> 7;        // 0: stage A (bf16), 1: stage B (fp32)
  const int ts = tid & 127;
  const int kslot = ts & 3;
  const int r0 = ts >> 2;
  unsigned char* wb0 = smem + mat * MATS + kslot * PLANE;

  // per-row source bases (B rows clamped; duplicates harmless, cols guarded)
  const u16* Arow[4];
  const float* Brow[4];
#pragma unroll
  for (int i = 0; i < 4; ++i) {
    Arow[i] = A + (size_t)(m0 + r0 + (i << 5)) * K;
    Brow[i] = B + (size_t)min(n0 + r0 + (i << 5), N - 1) * K;
  }

  const int lr = lane & 15, lk = lane >> 4;
  const int ardo = lk * PLANE + (wr * 64 + lr) * 16;
  const int brdo = MATS + lk * PLANE + (wc * 64 + lr) * 16;

  f32x4 acc[4][4] = {};
  float4 rgA_[4][2], rgB_[4][2];   // A path uses [i][0] raw bf16x8; B both
  const int NK = K >> 5;

  auto LOADT = [&](float4 (&rg)[4][2], int kt) {
    const int ko = (kt << 5) + (kslot << 3);
    if (mat == 0) {
#pragma unroll
      for (int i = 0; i < 4; ++i)
        rg[i][0] = *(const float4*)(Arow[i] + ko);
    } else {
#pragma unroll
      for (int i = 0; i < 4; ++i) {
        const float* p = Brow[i] + ko;
        rg[i][0] = *(const float4*)p;
        rg[i][1] = *(const float4*)(p + 4);
      }
    }
  };
  auto STORET = [&](const float4 (&rg)[4][2], int buf) {
    unsigned char* wb = wb0 + buf * BUFSZ;
    if (mat == 0) {
#pragma unroll
      for (int i = 0; i < 4; ++i)
        *(float4*)(wb + (r0 + (i << 5)) * 16) = rg[i][0];
    } else {
#pragma unroll
      for (int i = 0; i < 4; ++i) {
        union { bf16x8 v; u16 u[8]; } r;
        r.u[0] = f2bf(rg[i][0].x); r.u[1] = f2bf(rg[i][0].y);
        r.u[2] = f2bf(rg[i][0].z); r.u[3] = f2bf(rg[i][0].w);
        r.u[4] = f2bf(rg[i][1].x); r.u[5] = f2bf(rg[i][1].y);
        r.u[6] = f2bf(rg[i][1].z); r.u[7] = f2bf(rg[i][1].w);
        *(bf16x8*)(wb + (r0 + (i << 5)) * 16) = r.v;
      }
    }
  };
  auto COMPUTE = [&](int buf) {
    const unsigned char* base = smem + buf * BUFSZ;
    bf16x8 af[4], bfr[4];
#pragma unroll
    for (int f = 0; f < 4; ++f) {
      af[f]  = *(const bf16x8*)(base + ardo + f * 256);
      bfr[f] = *(const bf16x8*)(base + brdo + f * 256);
    }
#pragma unroll
    for (int fm = 0; fm < 4; ++fm)
#pragma unroll
      for (int fn = 0; fn < 4; ++fn)
        acc[fm][fn] = __builtin_amdgcn_mfma_f32_16x16x32_bf16(
            af[fm], bfr[fn], acc[fm][fn], 0, 0, 0);
  };

  LOADT(rgA_, 0);
  STORET(rgA_, 0);
  LOADT(rgB_, 1);
  __syncthreads();

  for (int kt = 0; kt < NK; kt += 2) {
    if (kt + 2 < NK) LOADT(rgA_, kt + 2);
    COMPUTE(0);
    STORET(rgB_, 1);
    __syncthreads();
    if (kt + 3 < NK) LOADT(rgB_, kt + 3);
    COMPUTE(1);
    if (kt + 2 < NK) {
      STORET(rgA_, 0);
      __syncthreads();
    }
  }

  const int orow0 = m0 + wr * 64 + (lk << 2);
  const int ocol0 = n0 + wc * 64 + lr;
#pragma unroll
  for (int fn = 0; fn < 4; ++fn) {
    int col = ocol0 + fn * 16;
    if (col >= N) continue;
    float bv = bias[col];
#pragma unroll
    for (int fm = 0; fm < 4; ++fm)
#pragma unroll
      for (int j = 0; j < 4; ++j) {
        int row = orow0 + fm * 16 + j;
        C[(size_t)row * N + col] = acc[fm][fn][j] + bv;
      }
  }
}

// ---------------------------------------------------------------------------
// Tiled flash attention (fp32 VALU) — unchanged from round 6.
// ---------------------------------------------------------------------------
__global__ __launch_bounds__(256) void k_flash(const float* __restrict__ q,
                                               const float* __restrict__ k,
                                               const float* __restrict__ v,
                                               u16* __restrict__ ctx,
                                               int T, int QS, int D,
                                               float scale) {
  __shared__ float Qs[64][68];
  __shared__ float KPs[64][68];
  __shared__ float Vs[64][68];
  int tid = threadIdx.x;
  int tx = tid & 15, ty = tid >> 4;
  int qt = gridDim.x - 1 - blockIdx.x;
  int q0 = qt << 6;
  int hoff = blockIdx.y << 6;

  {
    int row = tid >> 2;
    int col = (tid & 3) << 4;
    const float* src = q + (size_t)(q0 + row) * QS + hoff + col;
#pragma unroll
    for (int i = 0; i < 4; ++i) {
      float4 a = *(const float4*)(src + (i << 2));
      Qs[col + (i << 2) + 0][row] = a.x * scale;
      Qs[col + (i << 2) + 1][row] = a.y * scale;
      Qs[col + (i << 2) + 2][row] = a.z * scale;
      Qs[col + (i << 2) + 3][row] = a.w * scale;
    }
  }

  float m[4] = {-1e30f, -1e30f, -1e30f, -1e30f};
  float l[4] = {0.f, 0.f, 0.f, 0.f};
  float po[4][4] = {};

  for (int st = 0; st <= qt; ++st) {
    int s0 = st << 6;
    __syncthreads();
    {
      int row = tid >> 2;
      int col = (tid & 3) << 4;
      const float* ksrc = k + (size_t)(s0 + row) * QS + hoff + col;
      const float* vsrc = v + (size_t)(s0 + row) * QS + hoff + col;
#pragma unroll
      for (int i = 0; i < 4; ++i) {
        float4 a = *(const float4*)(ksrc + (i << 2));
        KPs[col + (i << 2) + 0][row] = a.x;
        KPs[col + (i << 2) + 1][row] = a.y;
        KPs[col + (i << 2) + 2][row] = a.z;
        KPs[col + (i << 2) + 3][row] = a.w;
        *(float4*)&Vs[row][col + (i << 2)] = *(const float4*)(vsrc + (i << 2));
      }
    }
    __syncthreads();

    float s[4][4] = {};
#pragma unroll 8
    for (int kk = 0; kk < 64; ++kk) {
      float4 a = *(const float4*)&Qs[kk][ty << 2];
      float4 b = *(const float4*)&KPs[kk][tx << 2];
      s[0][0] += a.x * b.x; s[0][1] += a.x * b.y; s[0][2] += a.x * b.z; s[0][3] += a.x * b.w;
      s[1][0] += a.y * b.x; s[1][1] += a.y * b.y; s[1][2] += a.y * b.z; s[1][3] += a.y * b.w;
      s[2][0] += a.z * b.x; s[2][1] += a.z * b.y; s[2][2] += a.z * b.z; s[2][3] += a.z * b.w;
      s[3][0] += a.w * b.x; s[3][1] += a.w * b.y; s[3][2] += a.w * b.z; s[3][3] += a.w * b.w;
    }

    if (st == qt) {
#pragma unroll
      for (int qi = 0; qi < 4; ++qi) {
        int qrow = (ty << 2) + qi;
#pragma unroll
        for (int si = 0; si < 4; ++si) {
          if ((tx << 2) + si > qrow) s[qi][si] = -1e30f;
        }
      }
    }

    float alpha[4];
#pragma unroll
    for (int qi = 0; qi < 4; ++qi) {
      float rmax = fmaxf(fmaxf(s[qi][0], s[qi][1]), fmaxf(s[qi][2], s[qi][3]));
      rmax = fmaxf(rmax, __shfl_xor(rmax, 1, 64));
      rmax = fmaxf(rmax, __shfl_xor(rmax, 2, 64));
      rmax = fmaxf(rmax, __shfl_xor(rmax, 4, 64));
      rmax = fmaxf(rmax, __shfl_xor(rmax, 8, 64));
      float mn = fmaxf(m[qi], rmax);
      alpha[qi] = __expf(m[qi] - mn);
      m[qi] = mn;
      float rsum = 0.f;
#pragma unroll
      for (int si = 0; si < 4; ++si) {
        float p = __expf(s[qi][si] - mn);
        s[qi][si] = p;
        rsum += p;
      }
      rsum += __shfl_xor(rsum, 1, 64);
      rsum += __shfl_xor(rsum, 2, 64);
      rsum += __shfl_xor(rsum, 4, 64);
      rsum += __shfl_xor(rsum, 8, 64);
      l[qi] = l[qi] * alpha[qi] + rsum;
      po[qi][0] *= alpha[qi]; po[qi][1] *= alpha[qi];
      po[qi][2] *= alpha[qi]; po[qi][3] *= alpha[qi];
    }

    __syncthreads();
#pragma unroll
    for (int si = 0; si < 4; ++si) {
      float4 p4 = make_float4(s[0][si], s[1][si], s[2][si], s[3][si]);
      *(float4*)&KPs[(tx << 2) + si][ty << 2] = p4;
    }
    __syncthreads();

#pragma unroll 8
    for (int kk = 0; kk < 64; ++kk) {
      float4 a = *(const float4*)&KPs[kk][ty << 2];
      float4 b = *(const float4*)&Vs[kk][tx << 2];
      po[0][0] += a.x * b.x; po[0][1] += a.x * b.y; po[0][2] += a.x * b.z; po[0][3] += a.x * b.w;
      po[1][0] += a.y * b.x; po[1][1] += a.y * b.y; po[1][2] += a.y * b.z; po[1][3] += a.y * b.w;
      po[2][0] += a.z * b.x; po[2][1] += a.z * b.y; po[2][2] += a.z * b.z; po[2][3] += a.z * b.w;
      po[3][0] += a.w * b.x; po[3][1] += a.w * b.y; po[3][2] += a.w * b.z; po[3][3] += a.w * b.w;
    }
  }

#pragma unroll
  for (int qi = 0; qi < 4; ++qi) {
    float inv = 1.0f / l[qi];
    ushort4 r;
    r.x = f2bf(po[qi][0] * inv); r.y = f2bf(po[qi][1] * inv);
    r.z = f2bf(po[qi][2] * inv); r.w = f2bf(po[qi][3] * inv);
    *(ushort4*)(ctx + (size_t)(q0 + (ty << 2) + qi) * D + hoff + (tx << 2)) = r;
  }
}

extern "C" void kernel_launch(void* const* d_in, const int* in_sizes, int n_in,
                              void* d_out, int out_size, void* d_ws, size_t ws_size,
                              hipStream_t stream) {
  const int T = 2048, D = 768, H = 12, L = 4, V = 50257, D4 = 3072;
  const size_t td = (size_t)T * D;

  const int* ids      = (const int*)d_in[0];
  const float* emb    = (const float*)d_in[1];
  const float* lm_bias= (const float*)d_in[2];
  const float* ln1_g  = (const float*)d_in[3];
  const float* ln1_b  = (const float*)d_in[4];
  const float* ln2_g  = (const float*)d_in[5];
  const float* ln2_b  = (const float*)d_in[6];
  const float* Wq     = (const float*)d_in[7];
  const float* bq     = (const float*)d_in[8];
  const float* Wk     = (const float*)d_in[9];
  const float* bk     = (const float*)d_in[10];
  const float* Wv     = (const float*)d_in[11];
  const float* bv     = (const float*)d_in[12];
  const float* Wo     = (const float*)d_in[13];
  const float* bo     = (const float*)d_in[14];
  const float* W1     = (const float*)d_in[15];
  const float* b1     = (const float*)d_in[16];
  const float* W2     = (const float*)d_in[17];
  const float* b2     = (const float*)d_in[18];
  const float* lnf_g  = (const float*)d_in[19];
  const float* lnf_b  = (const float*)d_in[20];
  float* out = (float*)d_out;

  // Scratch (as round 6):
  //   d_ws: x fp32 [T,768] + xnb bf16 [T,768] (9.4 MB).
  //   d_out front (~91 MB), all dead before the LM-head GEMM:
  //     wpool bf16 (56.6 MB) | bqkv fp32 | qkv fp32 [T,2304] |
  //     cbb bf16 [T,768] | hbb bf16 [T,3072]
  float* x  = (float*)d_ws;
  u16* xnb  = (u16*)(x + td);

  char* cur = (char*)d_out;
  u16* wpool = (u16*)cur;  cur += (size_t)4 * PER_L * 2;
  float* bqkv = (float*)cur; cur += (size_t)4 * 2304 * 4;
  float* qkv = (float*)cur;  cur += (size_t)3 * td * 4;
  u16* cbb = (u16*)cur;      cur += td * 2;
  u16* hbb = (u16*)cur;

  dim3 blk(256);

  k_castw<<<(4 * PER_L) / (256 * 8), blk, 0, stream>>>(Wq, Wk, Wv, Wo, W1, W2, wpool);
  k_castb<<<1, blk, 0, stream>>>(bq, bk, bv, bqkv);

  k_embed<<<T, blk, 0, stream>>>(ids, emb, x, T, D);

  for (int l = 0; l < L; ++l) {
    const u16* wl = wpool + (size_t)l * PER_L;

    k_layernorm<<<T, blk, 0, stream>>>(x, ln1_g + l * D, ln1_b + l * D, xnb, D);

    k_mm_bf<<<18 * 16, blk, 0, stream>>>(xnb, wl, bqkv + l * 2304, nullptr,
                                         qkv, T, 2304, 768, 0);

    dim3 ga(T / 64, H);
    k_flash<<<ga, blk, 0, stream>>>(qkv, qkv + 768, qkv + 1536, cbb,
                                    T, 2304, D, 0.125f);

    k_mm_bf<<<6 * 16, blk, 0, stream>>>(cbb, wl + QKVSZ, bo + l * D, x,
                                        x, T, 768, 768, 1);

    k_layernorm<<<T, blk, 0, stream>>>(x, ln2_g + l * D, ln2_b + l * D, xnb, D);

    k_mm_bf<<<24 * 16, blk, 0, stream>>>(xnb, wl + QKVSZ + OSZ, b1 + l * D4, nullptr,
                                         hbb, T, 3072, 768, 2);

    k_mm_bf<<<6 * 16, blk, 0, stream>>>(hbb, wl + QKVSZ + OSZ + W1SZ, b2 + l * D, x,
                                        x, T, 768, 3072, 1);
  }

  k_layernorm<<<T, blk, 0, stream>>>(x, lnf_g, lnf_b, xnb, D);

  k_mm_lmh<<<((V + 127) / 128) * 16, blk, 0, stream>>>(xnb, emb, lm_bias,
                                                       out, T, V, 768);
}

// Round 10
// 2490.834 us; speedup vs baseline: 1.5013x; 1.5013x over previous
//
#include <hip/hip_runtime.h>
#include <hip/hip_bf16.h>
#include <math.h>

// ---------------------------------------------------------------------------
// GPT-style transformer forward. Round 10: round-6 GEMM core + split-K grids.
// L=4, H=12, HD=64, D=768, V=50257, B=1, T=2048
// Round-9 post-mortem: depth-2 prefetch spilled in k_mm_lmh (WRITE_SIZE
// 4.1GB = 10x output -> scratch traffic), neutral in k_mm_bf. Staging-depth
// theory falsified (3 variants, MfmaUtil pinned ~13%).
// Surviving theory: occupancy. LMH (2.6 blocks/CU) = 332 TF; layer GEMMs
// (0.4-1.5 blocks/CU, <=1 wave/SIMD) = 70-100 TF. Fix: split-K so every
// layer GEMM has >=384-768 blocks; fp32 partials + k_red (sum+bias+res/gelu).
// GEMM inner loop = round-6 exactly (depth-1, VGPR 76). LMH = round-6 k_mm
// fp32-B path exactly.
// ---------------------------------------------------------------------------

typedef __attribute__((ext_vector_type(8))) short bf16x8;
typedef __attribute__((ext_vector_type(4))) float f32x4;
typedef unsigned short u16;

constexpr int OSZ   = 589824;        // 768*768
constexpr int QKVSZ = 3 * OSZ;
constexpr int W1SZ  = 2359296;       // 3072*768
constexpr int PER_L = QKVSZ + OSZ + W1SZ + W1SZ;  // 7077888

__device__ __forceinline__ u16 f2bf(float f) {
  unsigned u = __float_as_uint(f);
  u += 0x7FFFu + ((u >> 16) & 1u);
  return (u16)(u >> 16);
}

__device__ __forceinline__ float gelu_exact(float v) {
  return 0.5f * v * (1.0f + erff(v * 0.70710678118654752f));
}

__device__ __forceinline__ int xcd_swizzle(int orig, int nwg) {
  int xcd = orig & 7, lid = orig >> 3;
  int q8 = nwg >> 3, r8 = nwg & 7;
  return (xcd < r8 ? xcd * (q8 + 1) : r8 * (q8 + 1) + (xcd - r8) * q8) + lid;
}

__global__ __launch_bounds__(256) void k_embed(const int* __restrict__ ids,
                                               const float* __restrict__ emb,
                                               float* __restrict__ x,
                                               int T, int D) {
  int t = blockIdx.x;
  int id = ids[t];
  float neg_log = -logf(10000.0f) / (float)D;
  for (int d = threadIdx.x; d < D; d += 256) {
    float freq = expf((float)(d & ~1) * neg_log);
    float ang = (float)t * freq;
    float pe = (d & 1) ? cosf(ang) : sinf(ang);
    x[(size_t)t * D + d] = emb[(size_t)id * D + d] + pe;
  }
}

__global__ __launch_bounds__(256) void k_layernorm(const float* __restrict__ x,
                                                   const float* __restrict__ g,
                                                   const float* __restrict__ b,
                                                   u16* __restrict__ y,
                                                   int D) {
  int t = blockIdx.x;
  const float* xr = x + (size_t)t * D;
  __shared__ float red[256];
  float s = 0.f;
  for (int d = threadIdx.x; d < D; d += 256) s += xr[d];
  red[threadIdx.x] = s;
  __syncthreads();
  for (int st = 128; st > 0; st >>= 1) {
    if (threadIdx.x < st) red[threadIdx.x] += red[threadIdx.x + st];
    __syncthreads();
  }
  float mean = red[0] / (float)D;
  __syncthreads();
  float s2 = 0.f;
  for (int d = threadIdx.x; d < D; d += 256) {
    float u = xr[d] - mean;
    s2 += u * u;
  }
  red[threadIdx.x] = s2;
  __syncthreads();
  for (int st = 128; st > 0; st >>= 1) {
    if (threadIdx.x < st) red[threadIdx.x] += red[threadIdx.x + st];
    __syncthreads();
  }
  float rstd = rsqrtf(red[0] / (float)D + 1e-5f);
  u16* yr = y + (size_t)t * D;
  for (int d = threadIdx.x; d < D; d += 256)
    yr[d] = f2bf((xr[d] - mean) * rstd * g[d] + b[d]);
}

__global__ __launch_bounds__(256) void k_castw(const float* __restrict__ Wq,
                                               const float* __restrict__ Wk,
                                               const float* __restrict__ Wv,
                                               const float* __restrict__ Wo,
                                               const float* __restrict__ W1,
                                               const float* __restrict__ W2,
                                               u16* __restrict__ pool) {
  unsigned i8 = (blockIdx.x * 256u + threadIdx.x) * 8u;
  unsigned l = i8 / (unsigned)PER_L;
  unsigned off = i8 - l * (unsigned)PER_L;
  const float* src;
  if (off < (unsigned)QKVSZ) {
    unsigned w = off / (unsigned)OSZ;
    unsigned o = off - w * (unsigned)OSZ;
    src = (w == 0 ? Wq : (w == 1 ? Wk : Wv)) + (size_t)l * OSZ + o;
  } else if (off < (unsigned)(QKVSZ + OSZ)) {
    src = Wo + (size_t)l * OSZ + (off - QKVSZ);
  } else if (off < (unsigned)(QKVSZ + OSZ + W1SZ)) {
    src = W1 + (size_t)l * W1SZ + (off - (QKVSZ + OSZ));
  } else {
    src = W2 + (size_t)l * W1SZ + (off - (QKVSZ + OSZ + W1SZ));
  }
  float4 a = *(const float4*)src;
  float4 b = *(const float4*)(src + 4);
  union { bf16x8 v; u16 u[8]; } r;
  r.u[0] = f2bf(a.x); r.u[1] = f2bf(a.y); r.u[2] = f2bf(a.z); r.u[3] = f2bf(a.w);
  r.u[4] = f2bf(b.x); r.u[5] = f2bf(b.y); r.u[6] = f2bf(b.z); r.u[7] = f2bf(b.w);
  *(bf16x8*)(pool + i8) = r.v;
}

__global__ __launch_bounds__(256) void k_castb(const float* __restrict__ bq,
                                               const float* __restrict__ bk,
                                               const float* __restrict__ bv,
                                               float* __restrict__ bqkv) {
  for (int i = threadIdx.x; i < 4 * 2304; i += 256) {
    int l = i / 2304, c = i - l * 2304;
    int w = c / 768, cc = c - w * 768;
    bqkv[i] = (w == 0 ? bq : (w == 1 ? bk : bv))[l * 768 + cc];
  }
}

// ---------------------------------------------------------------------------
// k_mm_bf: round-6 inner loop (depth-1 reg staging, dbuf LDS) + split-K.
// mode 0: bias->fp32 C; mode 3: fp32 partial to P + kb*M*N (no bias).
// Grid = nbx*nby*ks blocks; tile=swz/ks (nb major, mb fast), kb=swz%ks.
// ---------------------------------------------------------------------------
__global__ __launch_bounds__(256) void k_mm_bf(const u16* __restrict__ A,
                                               const u16* __restrict__ B,
                                               const float* __restrict__ bias,
                                               void* __restrict__ Cv,
                                               int M, int N, int K,
                                               int mode, int ks) {
  constexpr int PLANE = 2080;
  constexpr int MATS  = 4 * PLANE;
  constexpr int BUFSZ = 2 * MATS;
  __shared__ alignas(16) unsigned char smem[2 * BUFSZ];

  const int nbx = (N + 127) >> 7;
  const int nby = M >> 7;
  const int swz = xcd_swizzle(blockIdx.x, nbx * nby * ks);
  const int tile = swz / ks;
  const int kb = swz - tile * ks;
  const int nb = tile / nby;
  const int mb = tile - nb * nby;
  const int m0 = mb << 7, n0 = nb << 7;

  const int tid = threadIdx.x;
  const int lane = tid & 63;
  const int wid = tid >> 6;
  const int wr = wid >> 1, wc = wid & 1;

  const int mat = tid >> 7;        // 0: stage A, 1: stage B
  const int ts = tid & 127;
  const int kslot = ts & 3;
  const int r0 = ts >> 2;
  const u16* gbase = mat ? B : A;
  const int gr0 = (mat ? n0 : m0) + r0;
  unsigned char* wb0 = smem + mat * MATS + kslot * PLANE;

  const int lr = lane & 15, lk = lane >> 4;
  const int ardo = lk * PLANE + (wr * 64 + lr) * 16;
  const int brdo = MATS + lk * PLANE + (wc * 64 + lr) * 16;

  f32x4 acc[4][4] = {};
  bf16x8 rg[4];
  const int Kc = K / ks;
  const int NK = Kc >> 5;
  const int K0 = kb * Kc;

  auto LOAD = [&](int kt) {
    const int ko = K0 + (kt << 5) + (kslot << 3);
#pragma unroll
    for (int i = 0; i < 4; ++i) {
      int grow = gr0 + (i << 5);
      if (mat) grow = min(grow, N - 1);   // clamp OOB B rows; cols guarded
      rg[i] = *(const bf16x8*)(gbase + (size_t)grow * K + ko);
    }
  };
  auto STORE = [&](int buf) {
    unsigned char* wb = wb0 + buf * BUFSZ;
#pragma unroll
    for (int i = 0; i < 4; ++i)
      *(bf16x8*)(wb + (r0 + (i << 5)) * 16) = rg[i];
  };
  auto COMPUTE = [&](int buf) {
    const unsigned char* base = smem + buf * BUFSZ;
    bf16x8 af[4], bfr[4];
#pragma unroll
    for (int f = 0; f < 4; ++f) {
      af[f]  = *(const bf16x8*)(base + ardo + f * 256);
      bfr[f] = *(const bf16x8*)(base + brdo + f * 256);
    }
#pragma unroll
    for (int fm = 0; fm < 4; ++fm)
#pragma unroll
      for (int fn = 0; fn < 4; ++fn)
        acc[fm][fn] = __builtin_amdgcn_mfma_f32_16x16x32_bf16(
            af[fm], bfr[fn], acc[fm][fn], 0, 0, 0);
  };

  LOAD(0);
  STORE(0);
  __syncthreads();
  int cur = 0;

  for (int kt = 0; kt < NK; ++kt) {
    if (kt + 1 < NK) LOAD(kt + 1);
    COMPUTE(cur);
    if (kt + 1 < NK) {
      STORE(cur ^ 1);
      __syncthreads();
      cur ^= 1;
    }
  }

  const int orow0 = m0 + wr * 64 + (lk << 2);
  const int ocol0 = n0 + wc * 64 + lr;
  if (mode == 3) {
    float* P = (float*)Cv + (size_t)kb * M * N;
#pragma unroll
    for (int fn = 0; fn < 4; ++fn) {
      int col = ocol0 + fn * 16;
      if (col >= N) continue;
#pragma unroll
      for (int fm = 0; fm < 4; ++fm)
#pragma unroll
        for (int j = 0; j < 4; ++j) {
          int row = orow0 + fm * 16 + j;
          P[(size_t)row * N + col] = acc[fm][fn][j];
        }
    }
  } else {
    float* C = (float*)Cv;
#pragma unroll
    for (int fn = 0; fn < 4; ++fn) {
      int col = ocol0 + fn * 16;
      if (col >= N) continue;
      float bv = bias[col];
#pragma unroll
      for (int fm = 0; fm < 4; ++fm)
#pragma unroll
        for (int j = 0; j < 4; ++j) {
          int row = orow0 + fm * 16 + j;
          C[(size_t)row * N + col] = acc[fm][fn][j] + bv;
        }
    }
  }
}

// ---------------------------------------------------------------------------
// k_red: out = sum_k P[k] + bias (+res / gelu->bf16). Grid-stride, float4.
// mode 0: fp32; mode 1: +res, fp32; mode 2: gelu, bf16.
// ---------------------------------------------------------------------------
__global__ __launch_bounds__(256) void k_red(const float* __restrict__ P,
                                             int ks,
                                             const float* __restrict__ bias,
                                             const float* __restrict__ res,
                                             void* __restrict__ out,
                                             int M, int N, int mode) {
  const size_t MN = (size_t)M * N;
  const size_t tot4 = MN >> 2;
  for (size_t i4 = (size_t)blockIdx.x * 256 + threadIdx.x; i4 < tot4;
       i4 += (size_t)gridDim.x * 256) {
    size_t i = i4 << 2;
    int col = (int)(i % (size_t)N);
    float4 s = *(const float4*)(P + i);
    for (int k = 1; k < ks; ++k) {
      float4 p = *(const float4*)(P + (size_t)k * MN + i);
      s.x += p.x; s.y += p.y; s.z += p.z; s.w += p.w;
    }
    s.x += bias[col]; s.y += bias[col + 1];
    s.z += bias[col + 2]; s.w += bias[col + 3];
    if (mode == 1) {
      float4 r = *(const float4*)(res + i);
      s.x += r.x; s.y += r.y; s.z += r.z; s.w += r.w;
      *(float4*)((float*)out + i) = s;
    } else if (mode == 2) {
      ushort4 o;
      o.x = f2bf(gelu_exact(s.x)); o.y = f2bf(gelu_exact(s.y));
      o.z = f2bf(gelu_exact(s.z)); o.w = f2bf(gelu_exact(s.w));
      *(ushort4*)((u16*)out + i) = o;
    } else {
      *(float4*)((float*)out + i) = s;
    }
  }
}

// ---------------------------------------------------------------------------
// k_mm_lmh: LM head, round-6 fp32-B path exactly (best measured: 476us).
// ---------------------------------------------------------------------------
__global__ __launch_bounds__(256) void k_mm_lmh(const u16* __restrict__ A,
                                                const float* __restrict__ B,
                                                const float* __restrict__ bias,
                                                float* __restrict__ C,
                                                int M, int N, int K) {
  constexpr int PLANE = 2080;
  constexpr int MATS  = 4 * PLANE;
  constexpr int BUFSZ = 2 * MATS;
  __shared__ alignas(16) unsigned char smem[2 * BUFSZ];

  const int nbx = (N + 127) >> 7;
  const int nby = M >> 7;
  const int swz = xcd_swizzle(blockIdx.x, nbx * nby);
  const int nb = swz / nby;
  const int mb = swz - nb * nby;
  const int m0 = mb << 7, n0 = nb << 7;

  const int tid = threadIdx.x;
  const int lane = tid & 63;
  const int wid = tid >> 6;
  const int wr = wid >> 1, wc = wid & 1;

  const int mat = tid >> 7;
  const int ts = tid & 127;
  const int kslot = ts & 3;
  const int r0 = ts >> 2;
  const int gr0 = (mat ? n0 : m0) + r0;
  const u16* Abf = A;
  const float* Bf = B;
  unsigned char* wb0 = smem + mat * MATS + kslot * PLANE;

  const int lr = lane & 15, lk = lane >> 4;
  const int ardo = lk * PLANE + (wr * 64 + lr) * 16;
  const int brdo = MATS + lk * PLANE + (wc * 64 + lr) * 16;

  f32x4 acc[4][4] = {};
  float4 rg[4][2];  // A path: rg[i][0] raw bf16x8; B path: 8 fp32
  const int NK = K >> 5;

  auto LOAD = [&](int kt) {
    const int ko = (kt << 5) + (kslot << 3);
    if (mat == 0) {
#pragma unroll
      for (int i = 0; i < 4; ++i)
        rg[i][0] = *(const float4*)(Abf + (size_t)(gr0 + (i << 5)) * K + ko);
    } else {
#pragma unroll
      for (int i = 0; i < 4; ++i) {
        int grow = gr0 + (i << 5);
        if (grow < N) {
          const float* p = Bf + (size_t)grow * K + ko;
          rg[i][0] = *(const float4*)p;
          rg[i][1] = *(const float4*)(p + 4);
        }
        // OOB rows: keep zeros from prologue zero-fill
      }
    }
  };
  auto STORE = [&](int buf) {
    unsigned char* wb = wb0 + buf * BUFSZ;
    if (mat == 0) {
#pragma unroll
      for (int i = 0; i < 4; ++i)
        *(float4*)(wb + (r0 + (i << 5)) * 16) = rg[i][0];
    } else {
#pragma unroll
      for (int i = 0; i < 4; ++i) {
        union { bf16x8 v; u16 u[8]; } r;
        r.u[0] = f2bf(rg[i][0].x); r.u[1] = f2bf(rg[i][0].y);
        r.u[2] = f2bf(rg[i][0].z); r.u[3] = f2bf(rg[i][0].w);
        r.u[4] = f2bf(rg[i][1].x); r.u[5] = f2bf(rg[i][1].y);
        r.u[6] = f2bf(rg[i][1].z); r.u[7] = f2bf(rg[i][1].w);
        *(bf16x8*)(wb + (r0 + (i << 5)) * 16) = r.v;
      }
    }
  };
  auto COMPUTE = [&](int buf) {
    const unsigned char* base = smem + buf * BUFSZ;
    bf16x8 af[4], bfr[4];
#pragma unroll
    for (int f = 0; f < 4; ++f) {
      af[f]  = *(const bf16x8*)(base + ardo + f * 256);
      bfr[f] = *(const bf16x8*)(base + brdo + f * 256);
    }
#pragma unroll
    for (int fm = 0; fm < 4; ++fm)
#pragma unroll
      for (int fn = 0; fn < 4; ++fn)
        acc[fm][fn] = __builtin_amdgcn_mfma_f32_16x16x32_bf16(
            af[fm], bfr[fn], acc[fm][fn], 0, 0, 0);
  };

  // prologue: zero-fill (OOB B rows stay zero all K-steps), then load tile 0
#pragma unroll
  for (int i = 0; i < 4; ++i) {
    rg[i][0] = make_float4(0.f, 0.f, 0.f, 0.f);
    rg[i][1] = make_float4(0.f, 0.f, 0.f, 0.f);
  }
  LOAD(0);
  STORE(0);
  __syncthreads();
  int cur = 0;

  for (int kt = 0; kt < NK; ++kt) {
    if (kt + 1 < NK) LOAD(kt + 1);
    COMPUTE(cur);
    if (kt + 1 < NK) {
      STORE(cur ^ 1);
      __syncthreads();
      cur ^= 1;
    }
  }

  const int orow0 = m0 + wr * 64 + (lk << 2);
  const int ocol0 = n0 + wc * 64 + lr;
#pragma unroll
  for (int fn = 0; fn < 4; ++fn) {
    int col = ocol0 + fn * 16;
    if (col >= N) continue;
    float bv = bias[col];
#pragma unroll
    for (int fm = 0; fm < 4; ++fm)
#pragma unroll
      for (int j = 0; j < 4; ++j) {
        int row = orow0 + fm * 16 + j;
        C[(size_t)row * N + col] = acc[fm][fn][j] + bv;
      }
  }
}

// ---------------------------------------------------------------------------
// Tiled flash attention (fp32 VALU) — unchanged.
// ---------------------------------------------------------------------------
__global__ __launch_bounds__(256) void k_flash(const float* __restrict__ q,
                                               const float* __restrict__ k,
                                               const float* __restrict__ v,
                                               u16* __restrict__ ctx,
                                               int T, int QS, int D,
                                               float scale) {
  __shared__ float Qs[64][68];
  __shared__ float KPs[64][68];
  __shared__ float Vs[64][68];
  int tid = threadIdx.x;
  int tx = tid & 15, ty = tid >> 4;
  int qt = gridDim.x - 1 - blockIdx.x;
  int q0 = qt << 6;
  int hoff = blockIdx.y << 6;

  {
    int row = tid >> 2;
    int col = (tid & 3) << 4;
    const float* src = q + (size_t)(q0 + row) * QS + hoff + col;
#pragma unroll
    for (int i = 0; i < 4; ++i) {
      float4 a = *(const float4*)(src + (i << 2));
      Qs[col + (i << 2) + 0][row] = a.x * scale;
      Qs[col + (i << 2) + 1][row] = a.y * scale;
      Qs[col + (i << 2) + 2][row] = a.z * scale;
      Qs[col + (i << 2) + 3][row] = a.w * scale;
    }
  }

  float m[4] = {-1e30f, -1e30f, -1e30f, -1e30f};
  float l[4] = {0.f, 0.f, 0.f, 0.f};
  float po[4][4] = {};

  for (int st = 0; st <= qt; ++st) {
    int s0 = st << 6;
    __syncthreads();
    {
      int row = tid >> 2;
      int col = (tid & 3) << 4;
      const float* ksrc = k + (size_t)(s0 + row) * QS + hoff + col;
      const float* vsrc = v + (size_t)(s0 + row) * QS + hoff + col;
#pragma unroll
      for (int i = 0; i < 4; ++i) {
        float4 a = *(const float4*)(ksrc + (i << 2));
        KPs[col + (i << 2) + 0][row] = a.x;
        KPs[col + (i << 2) + 1][row] = a.y;
        KPs[col + (i << 2) + 2][row] = a.z;
        KPs[col + (i << 2) + 3][row] = a.w;
        *(float4*)&Vs[row][col + (i << 2)] = *(const float4*)(vsrc + (i << 2));
      }
    }
    __syncthreads();

    float s[4][4] = {};
#pragma unroll 8
    for (int kk = 0; kk < 64; ++kk) {
      float4 a = *(const float4*)&Qs[kk][ty << 2];
      float4 b = *(const float4*)&KPs[kk][tx << 2];
      s[0][0] += a.x * b.x; s[0][1] += a.x * b.y; s[0][2] += a.x * b.z; s[0][3] += a.x * b.w;
      s[1][0] += a.y * b.x; s[1][1] += a.y * b.y; s[1][2] += a.y * b.z; s[1][3] += a.y * b.w;
      s[2][0] += a.z * b.x; s[2][1] += a.z * b.y; s[2][2] += a.z * b.z; s[2][3] += a.z * b.w;
      s[3][0] += a.w * b.x; s[3][1] += a.w * b.y; s[3][2] += a.w * b.z; s[3][3] += a.w * b.w;
    }

    if (st == qt) {
#pragma unroll
      for (int qi = 0; qi < 4; ++qi) {
        int qrow = (ty << 2) + qi;
#pragma unroll
        for (int si = 0; si < 4; ++si) {
          if ((tx << 2) + si > qrow) s[qi][si] = -1e30f;
        }
      }
    }

    float alpha[4];
#pragma unroll
    for (int qi = 0; qi < 4; ++qi) {
      float rmax = fmaxf(fmaxf(s[qi][0], s[qi][1]), fmaxf(s[qi][2], s[qi][3]));
      rmax = fmaxf(rmax, __shfl_xor(rmax, 1, 64));
      rmax = fmaxf(rmax, __shfl_xor(rmax, 2, 64));
      rmax = fmaxf(rmax, __shfl_xor(rmax, 4, 64));
      rmax = fmaxf(rmax, __shfl_xor(rmax, 8, 64));
      float mn = fmaxf(m[qi], rmax);
      alpha[qi] = __expf(m[qi] - mn);
      m[qi] = mn;
      float rsum = 0.f;
#pragma unroll
      for (int si = 0; si < 4; ++si) {
        float p = __expf(s[qi][si] - mn);
        s[qi][si] = p;
        rsum += p;
      }
      rsum += __shfl_xor(rsum, 1, 64);
      rsum += __shfl_xor(rsum, 2, 64);
      rsum += __shfl_xor(rsum, 4, 64);
      rsum += __shfl_xor(rsum, 8, 64);
      l[qi] = l[qi] * alpha[qi] + rsum;
      po[qi][0] *= alpha[qi]; po[qi][1] *= alpha[qi];
      po[qi][2] *= alpha[qi]; po[qi][3] *= alpha[qi];
    }

    __syncthreads();
#pragma unroll
    for (int si = 0; si < 4; ++si) {
      float4 p4 = make_float4(s[0][si], s[1][si], s[2][si], s[3][si]);
      *(float4*)&KPs[(tx << 2) + si][ty << 2] = p4;
    }
    __syncthreads();

#pragma unroll 8
    for (int kk = 0; kk < 64; ++kk) {
      float4 a = *(const float4*)&KPs[kk][ty << 2];
      float4 b = *(const float4*)&Vs[kk][tx << 2];
      po[0][0] += a.x * b.x; po[0][1] += a.x * b.y; po[0][2] += a.x * b.z; po[0][3] += a.x * b.w;
      po[1][0] += a.y * b.x; po[1][1] += a.y * b.y; po[1][2] += a.y * b.z; po[1][3] += a.y * b.w;
      po[2][0] += a.z * b.x; po[2][1] += a.z * b.y; po[2][2] += a.z * b.z; po[2][3] += a.z * b.w;
      po[3][0] += a.w * b.x; po[3][1] += a.w * b.y; po[3][2] += a.w * b.z; po[3][3] += a.w * b.w;
    }
  }

#pragma unroll
  for (int qi = 0; qi < 4; ++qi) {
    float inv = 1.0f / l[qi];
    ushort4 r;
    r.x = f2bf(po[qi][0] * inv); r.y = f2bf(po[qi][1] * inv);
    r.z = f2bf(po[qi][2] * inv); r.w = f2bf(po[qi][3] * inv);
    *(ushort4*)(ctx + (size_t)(q0 + (ty << 2) + qi) * D + hoff + (tx << 2)) = r;
  }
}

extern "C" void kernel_launch(void* const* d_in, const int* in_sizes, int n_in,
                              void* d_out, int out_size, void* d_ws, size_t ws_size,
                              hipStream_t stream) {
  const int T = 2048, D = 768, H = 12, L = 4, V = 50257, D4 = 3072;
  const size_t td = (size_t)T * D;

  const int* ids      = (const int*)d_in[0];
  const float* emb    = (const float*)d_in[1];
  const float* lm_bias= (const float*)d_in[2];
  const float* ln1_g  = (const float*)d_in[3];
  const float* ln1_b  = (const float*)d_in[4];
  const float* ln2_g  = (const float*)d_in[5];
  const float* ln2_b  = (const float*)d_in[6];
  const float* Wq     = (const float*)d_in[7];
  const float* bq     = (const float*)d_in[8];
  const float* Wk     = (const float*)d_in[9];
  const float* bk     = (const float*)d_in[10];
  const float* Wv     = (const float*)d_in[11];
  const float* bv     = (const float*)d_in[12];
  const float* Wo     = (const float*)d_in[13];
  const float* bo     = (const float*)d_in[14];
  const float* W1     = (const float*)d_in[15];
  const float* b1     = (const float*)d_in[16];
  const float* W2     = (const float*)d_in[17];
  const float* b2     = (const float*)d_in[18];
  const float* lnf_g  = (const float*)d_in[19];
  const float* lnf_b  = (const float*)d_in[20];
  float* out = (float*)d_out;

  // Scratch:
  //   d_ws: x fp32 [T,768] + xnb bf16 [T,768] (9.4 MB).
  //   d_out front (~205 MB of 412 MB), all dead before the LM-head GEMM
  //   (LMH reads only xnb in ws + emb/lm_bias inputs):
  //     wpool 56.6 | bqkv | qkv fp32 18.9 | cbb 3.1 | hbb 12.6 |
  //     pqkv 37.7 | pw1 50.3 | po4 25.2  (fp32 split-K partials)
  float* x  = (float*)d_ws;
  u16* xnb  = (u16*)(x + td);

  char* cur = (char*)d_out;
  u16* wpool = (u16*)cur;  cur += (size_t)4 * PER_L * 2;
  float* bqkv = (float*)cur; cur += (size_t)4 * 2304 * 4;
  float* qkv = (float*)cur;  cur += (size_t)3 * td * 4;
  u16* cbb = (u16*)cur;      cur += td * 2;
  u16* hbb = (u16*)cur;      cur += (size_t)T * D4 * 2;
  float* pqkv = (float*)cur; cur += (size_t)2 * T * 2304 * 4;
  float* pw1 = (float*)cur;  cur += (size_t)2 * T * D4 * 4;
  float* po4 = (float*)cur;  // 4*T*768*4

  dim3 blk(256);

  k_castw<<<(4 * PER_L) / (256 * 8), blk, 0, stream>>>(Wq, Wk, Wv, Wo, W1, W2, wpool);
  k_castb<<<1, blk, 0, stream>>>(bq, bk, bv, bqkv);

  k_embed<<<T, blk, 0, stream>>>(ids, emb, x, T, D);

  for (int l = 0; l < L; ++l) {
    const u16* wl = wpool + (size_t)l * PER_L;

    k_layernorm<<<T, blk, 0, stream>>>(x, ln1_g + l * D, ln1_b + l * D, xnb, D);

    // QKV: split-K=2, 576 blocks -> partials -> reduce(+bias) to fp32 qkv
    k_mm_bf<<<18 * 16 * 2, blk, 0, stream>>>(xnb, wl, nullptr, pqkv,
                                             T, 2304, 768, 3, 2);
    k_red<<<2048, blk, 0, stream>>>(pqkv, 2, bqkv + l * 2304, nullptr,
                                    qkv, T, 2304, 0);

    dim3 ga(T / 64, H);
    k_flash<<<ga, blk, 0, stream>>>(qkv, qkv + 768, qkv + 1536, cbb,
                                    T, 2304, D, 0.125f);

    // O-proj: split-K=4, 384 blocks -> reduce(+bias+res) into x
    k_mm_bf<<<6 * 16 * 4, blk, 0, stream>>>(cbb, wl + QKVSZ, nullptr, po4,
                                            T, 768, 768, 3, 4);
    k_red<<<1536, blk, 0, stream>>>(po4, 4, bo + l * D, x, x, T, 768, 1);

    k_layernorm<<<T, blk, 0, stream>>>(x, ln2_g + l * D, ln2_b + l * D, xnb, D);

    // W1: split-K=2, 768 blocks -> reduce(+bias, gelu) to bf16 hbb
    k_mm_bf<<<24 * 16 * 2, blk, 0, stream>>>(xnb, wl + QKVSZ + OSZ, nullptr, pw1,
                                             T, 3072, 768, 3, 2);
    k_red<<<2048, blk, 0, stream>>>(pw1, 2, b1 + l * D4, nullptr,
                                    hbb, T, 3072, 2);

    // W2: split-K=4, 384 blocks -> reduce(+bias+res) into x
    k_mm_bf<<<6 * 16 * 4, blk, 0, stream>>>(hbb, wl + QKVSZ + OSZ + W1SZ, nullptr,
                                            po4, T, 768, 3072, 3, 4);
    k_red<<<1536, blk, 0, stream>>>(po4, 4, b2 + l * D, x, x, T, 768, 1);
  }

  k_layernorm<<<T, blk, 0, stream>>>(x, lnf_g, lnf_b, xnb, D);

  k_mm_lmh<<<((V + 127) / 128) * 16, blk, 0, stream>>>(xnb, emb, lm_bias,
                                                       out, T, V, 768);
}

// Round 11
// 1806.822 us; speedup vs baseline: 2.0696x; 1.3786x over previous
//
#include <hip/hip_runtime.h>
#include <hip/hip_bf16.h>
#include <math.h>

// ---------------------------------------------------------------------------
// GPT-style transformer forward. Round 11: MFMA flash attention.
// L=4, H=12, HD=64, D=768, V=50257, B=1, T=2048
// Round-10 (split-K) WIN: 2724->2491us; GEMM structure frozen this round.
// Remaining: k_flash fp32-VALU = 110us/layer (440 total) with matrix pipe
// idle. Replaced with k_flashm: bf16 qkv (k_red mode 3), per block
// (head, 64q-tile), 4 waves x 16 q-rows; Q frags in regs; K LDS row-major,
// V LDS transposed (pitch 176 -> ~2-way ds conflicts = free); S via 8
// MFMA/wave; wave-parallel online softmax (shfl_xor in 16-lane groups);
// P->bf16 via per-wave LDS slab (no cross-wave sync); PV 8 MFMA/wave.
// LDS 33.8KB -> all 384 blocks co-resident.
// ---------------------------------------------------------------------------

typedef __attribute__((ext_vector_type(8))) short bf16x8;
typedef __attribute__((ext_vector_type(4))) float f32x4;
typedef unsigned short u16;

constexpr int OSZ   = 589824;        // 768*768
constexpr int QKVSZ = 3 * OSZ;
constexpr int W1SZ  = 2359296;       // 3072*768
constexpr int PER_L = QKVSZ + OSZ + W1SZ + W1SZ;  // 7077888

__device__ __forceinline__ u16 f2bf(float f) {
  unsigned u = __float_as_uint(f);
  u += 0x7FFFu + ((u >> 16) & 1u);
  return (u16)(u >> 16);
}

__device__ __forceinline__ float gelu_exact(float v) {
  return 0.5f * v * (1.0f + erff(v * 0.70710678118654752f));
}

__device__ __forceinline__ int xcd_swizzle(int orig, int nwg) {
  int xcd = orig & 7, lid = orig >> 3;
  int q8 = nwg >> 3, r8 = nwg & 7;
  return (xcd < r8 ? xcd * (q8 + 1) : r8 * (q8 + 1) + (xcd - r8) * q8) + lid;
}

__global__ __launch_bounds__(256) void k_embed(const int* __restrict__ ids,
                                               const float* __restrict__ emb,
                                               float* __restrict__ x,
                                               int T, int D) {
  int t = blockIdx.x;
  int id = ids[t];
  float neg_log = -logf(10000.0f) / (float)D;
  for (int d = threadIdx.x; d < D; d += 256) {
    float freq = expf((float)(d & ~1) * neg_log);
    float ang = (float)t * freq;
    float pe = (d & 1) ? cosf(ang) : sinf(ang);
    x[(size_t)t * D + d] = emb[(size_t)id * D + d] + pe;
  }
}

__global__ __launch_bounds__(256) void k_layernorm(const float* __restrict__ x,
                                                   const float* __restrict__ g,
                                                   const float* __restrict__ b,
                                                   u16* __restrict__ y,
                                                   int D) {
  int t = blockIdx.x;
  const float* xr = x + (size_t)t * D;
  __shared__ float red[256];
  float s = 0.f;
  for (int d = threadIdx.x; d < D; d += 256) s += xr[d];
  red[threadIdx.x] = s;
  __syncthreads();
  for (int st = 128; st > 0; st >>= 1) {
    if (threadIdx.x < st) red[threadIdx.x] += red[threadIdx.x + st];
    __syncthreads();
  }
  float mean = red[0] / (float)D;
  __syncthreads();
  float s2 = 0.f;
  for (int d = threadIdx.x; d < D; d += 256) {
    float u = xr[d] - mean;
    s2 += u * u;
  }
  red[threadIdx.x] = s2;
  __syncthreads();
  for (int st = 128; st > 0; st >>= 1) {
    if (threadIdx.x < st) red[threadIdx.x] += red[threadIdx.x + st];
    __syncthreads();
  }
  float rstd = rsqrtf(red[0] / (float)D + 1e-5f);
  u16* yr = y + (size_t)t * D;
  for (int d = threadIdx.x; d < D; d += 256)
    yr[d] = f2bf((xr[d] - mean) * rstd * g[d] + b[d]);
}

__global__ __launch_bounds__(256) void k_castw(const float* __restrict__ Wq,
                                               const float* __restrict__ Wk,
                                               const float* __restrict__ Wv,
                                               const float* __restrict__ Wo,
                                               const float* __restrict__ W1,
                                               const float* __restrict__ W2,
                                               u16* __restrict__ pool) {
  unsigned i8 = (blockIdx.x * 256u + threadIdx.x) * 8u;
  unsigned l = i8 / (unsigned)PER_L;
  unsigned off = i8 - l * (unsigned)PER_L;
  const float* src;
  if (off < (unsigned)QKVSZ) {
    unsigned w = off / (unsigned)OSZ;
    unsigned o = off - w * (unsigned)OSZ;
    src = (w == 0 ? Wq : (w == 1 ? Wk : Wv)) + (size_t)l * OSZ + o;
  } else if (off < (unsigned)(QKVSZ + OSZ)) {
    src = Wo + (size_t)l * OSZ + (off - QKVSZ);
  } else if (off < (unsigned)(QKVSZ + OSZ + W1SZ)) {
    src = W1 + (size_t)l * W1SZ + (off - (QKVSZ + OSZ));
  } else {
    src = W2 + (size_t)l * W1SZ + (off - (QKVSZ + OSZ + W1SZ));
  }
  float4 a = *(const float4*)src;
  float4 b = *(const float4*)(src + 4);
  union { bf16x8 v; u16 u[8]; } r;
  r.u[0] = f2bf(a.x); r.u[1] = f2bf(a.y); r.u[2] = f2bf(a.z); r.u[3] = f2bf(a.w);
  r.u[4] = f2bf(b.x); r.u[5] = f2bf(b.y); r.u[6] = f2bf(b.z); r.u[7] = f2bf(b.w);
  *(bf16x8*)(pool + i8) = r.v;
}

__global__ __launch_bounds__(256) void k_castb(const float* __restrict__ bq,
                                               const float* __restrict__ bk,
                                               const float* __restrict__ bv,
                                               float* __restrict__ bqkv) {
  for (int i = threadIdx.x; i < 4 * 2304; i += 256) {
    int l = i / 2304, c = i - l * 2304;
    int w = c / 768, cc = c - w * 768;
    bqkv[i] = (w == 0 ? bq : (w == 1 ? bk : bv))[l * 768 + cc];
  }
}

// ---------------------------------------------------------------------------
// k_mm_bf: round-10 (round-6 core) split-K GEMM. mode 3: fp32 partials.
// ---------------------------------------------------------------------------
__global__ __launch_bounds__(256) void k_mm_bf(const u16* __restrict__ A,
                                               const u16* __restrict__ B,
                                               const float* __restrict__ bias,
                                               void* __restrict__ Cv,
                                               int M, int N, int K,
                                               int mode, int ks) {
  constexpr int PLANE = 2080;
  constexpr int MATS  = 4 * PLANE;
  constexpr int BUFSZ = 2 * MATS;
  __shared__ alignas(16) unsigned char smem[2 * BUFSZ];

  const int nbx = (N + 127) >> 7;
  const int nby = M >> 7;
  const int swz = xcd_swizzle(blockIdx.x, nbx * nby * ks);
  const int tile = swz / ks;
  const int kb = swz - tile * ks;
  const int nb = tile / nby;
  const int mb = tile - nb * nby;
  const int m0 = mb << 7, n0 = nb << 7;

  const int tid = threadIdx.x;
  const int lane = tid & 63;
  const int wid = tid >> 6;
  const int wr = wid >> 1, wc = wid & 1;

  const int mat = tid >> 7;
  const int ts = tid & 127;
  const int kslot = ts & 3;
  const int r0 = ts >> 2;
  const u16* gbase = mat ? B : A;
  const int gr0 = (mat ? n0 : m0) + r0;
  unsigned char* wb0 = smem + mat * MATS + kslot * PLANE;

  const int lr = lane & 15, lk = lane >> 4;
  const int ardo = lk * PLANE + (wr * 64 + lr) * 16;
  const int brdo = MATS + lk * PLANE + (wc * 64 + lr) * 16;

  f32x4 acc[4][4] = {};
  bf16x8 rg[4];
  const int Kc = K / ks;
  const int NK = Kc >> 5;
  const int K0 = kb * Kc;

  auto LOAD = [&](int kt) {
    const int ko = K0 + (kt << 5) + (kslot << 3);
#pragma unroll
    for (int i = 0; i < 4; ++i) {
      int grow = gr0 + (i << 5);
      if (mat) grow = min(grow, N - 1);
      rg[i] = *(const bf16x8*)(gbase + (size_t)grow * K + ko);
    }
  };
  auto STORE = [&](int buf) {
    unsigned char* wb = wb0 + buf * BUFSZ;
#pragma unroll
    for (int i = 0; i < 4; ++i)
      *(bf16x8*)(wb + (r0 + (i << 5)) * 16) = rg[i];
  };
  auto COMPUTE = [&](int buf) {
    const unsigned char* base = smem + buf * BUFSZ;
    bf16x8 af[4], bfr[4];
#pragma unroll
    for (int f = 0; f < 4; ++f) {
      af[f]  = *(const bf16x8*)(base + ardo + f * 256);
      bfr[f] = *(const bf16x8*)(base + brdo + f * 256);
    }
#pragma unroll
    for (int fm = 0; fm < 4; ++fm)
#pragma unroll
      for (int fn = 0; fn < 4; ++fn)
        acc[fm][fn] = __builtin_amdgcn_mfma_f32_16x16x32_bf16(
            af[fm], bfr[fn], acc[fm][fn], 0, 0, 0);
  };

  LOAD(0);
  STORE(0);
  __syncthreads();
  int cur = 0;

  for (int kt = 0; kt < NK; ++kt) {
    if (kt + 1 < NK) LOAD(kt + 1);
    COMPUTE(cur);
    if (kt + 1 < NK) {
      STORE(cur ^ 1);
      __syncthreads();
      cur ^= 1;
    }
  }

  const int orow0 = m0 + wr * 64 + (lk << 2);
  const int ocol0 = n0 + wc * 64 + lr;
  if (mode == 3) {
    float* P = (float*)Cv + (size_t)kb * M * N;
#pragma unroll
    for (int fn = 0; fn < 4; ++fn) {
      int col = ocol0 + fn * 16;
      if (col >= N) continue;
#pragma unroll
      for (int fm = 0; fm < 4; ++fm)
#pragma unroll
        for (int j = 0; j < 4; ++j) {
          int row = orow0 + fm * 16 + j;
          P[(size_t)row * N + col] = acc[fm][fn][j];
        }
    }
  } else {
    float* C = (float*)Cv;
#pragma unroll
    for (int fn = 0; fn < 4; ++fn) {
      int col = ocol0 + fn * 16;
      if (col >= N) continue;
      float bv = bias[col];
#pragma unroll
      for (int fm = 0; fm < 4; ++fm)
#pragma unroll
        for (int j = 0; j < 4; ++j) {
          int row = orow0 + fm * 16 + j;
          C[(size_t)row * N + col] = acc[fm][fn][j] + bv;
        }
    }
  }
}

// ---------------------------------------------------------------------------
// k_red: out = sum_k P[k] + bias (+res / gelu / ->bf16). Grid-stride, float4.
// mode 0: fp32; mode 1: +res fp32; mode 2: gelu bf16; mode 3: bf16.
// ---------------------------------------------------------------------------
__global__ __launch_bounds__(256) void k_red(const float* __restrict__ P,
                                             int ks,
                                             const float* __restrict__ bias,
                                             const float* __restrict__ res,
                                             void* __restrict__ out,
                                             int M, int N, int mode) {
  const size_t MN = (size_t)M * N;
  const size_t tot4 = MN >> 2;
  for (size_t i4 = (size_t)blockIdx.x * 256 + threadIdx.x; i4 < tot4;
       i4 += (size_t)gridDim.x * 256) {
    size_t i = i4 << 2;
    int col = (int)(i % (size_t)N);
    float4 s = *(const float4*)(P + i);
    for (int k = 1; k < ks; ++k) {
      float4 p = *(const float4*)(P + (size_t)k * MN + i);
      s.x += p.x; s.y += p.y; s.z += p.z; s.w += p.w;
    }
    s.x += bias[col]; s.y += bias[col + 1];
    s.z += bias[col + 2]; s.w += bias[col + 3];
    if (mode == 1) {
      float4 r = *(const float4*)(res + i);
      s.x += r.x; s.y += r.y; s.z += r.z; s.w += r.w;
      *(float4*)((float*)out + i) = s;
    } else if (mode == 2) {
      ushort4 o;
      o.x = f2bf(gelu_exact(s.x)); o.y = f2bf(gelu_exact(s.y));
      o.z = f2bf(gelu_exact(s.z)); o.w = f2bf(gelu_exact(s.w));
      *(ushort4*)((u16*)out + i) = o;
    } else if (mode == 3) {
      ushort4 o;
      o.x = f2bf(s.x); o.y = f2bf(s.y); o.z = f2bf(s.z); o.w = f2bf(s.w);
      *(ushort4*)((u16*)out + i) = o;
    } else {
      *(float4*)((float*)out + i) = s;
    }
  }
}

// ---------------------------------------------------------------------------
// k_mm_lmh: LM head, round-10 (round-6 fp32-B) exactly.
// ---------------------------------------------------------------------------
__global__ __launch_bounds__(256) void k_mm_lmh(const u16* __restrict__ A,
                                                const float* __restrict__ B,
                                                const float* __restrict__ bias,
                                                float* __restrict__ C,
                                                int M, int N, int K) {
  constexpr int PLANE = 2080;
  constexpr int MATS  = 4 * PLANE;
  constexpr int BUFSZ = 2 * MATS;
  __shared__ alignas(16) unsigned char smem[2 * BUFSZ];

  const int nbx = (N + 127) >> 7;
  const int nby = M >> 7;
  const int swz = xcd_swizzle(blockIdx.x, nbx * nby);
  const int nb = swz / nby;
  const int mb = swz - nb * nby;
  const int m0 = mb << 7, n0 = nb << 7;

  const int tid = threadIdx.x;
  const int lane = tid & 63;
  const int wid = tid >> 6;
  const int wr = wid >> 1, wc = wid & 1;

  const int mat = tid >> 7;
  const int ts = tid & 127;
  const int kslot = ts & 3;
  const int r0 = ts >> 2;
  const int gr0 = (mat ? n0 : m0) + r0;
  const u16* Abf = A;
  const float* Bf = B;
  unsigned char* wb0 = smem + mat * MATS + kslot * PLANE;

  const int lr = lane & 15, lk = lane >> 4;
  const int ardo = lk * PLANE + (wr * 64 + lr) * 16;
  const int brdo = MATS + lk * PLANE + (wc * 64 + lr) * 16;

  f32x4 acc[4][4] = {};
  float4 rg[4][2];
  const int NK = K >> 5;

  auto LOAD = [&](int kt) {
    const int ko = (kt << 5) + (kslot << 3);
    if (mat == 0) {
#pragma unroll
      for (int i = 0; i < 4; ++i)
        rg[i][0] = *(const float4*)(Abf + (size_t)(gr0 + (i << 5)) * K + ko);
    } else {
#pragma unroll
      for (int i = 0; i < 4; ++i) {
        int grow = gr0 + (i << 5);
        if (grow < N) {
          const float* p = Bf + (size_t)grow * K + ko;
          rg[i][0] = *(const float4*)p;
          rg[i][1] = *(const float4*)(p + 4);
        }
      }
    }
  };
  auto STORE = [&](int buf) {
    unsigned char* wb = wb0 + buf * BUFSZ;
    if (mat == 0) {
#pragma unroll
      for (int i = 0; i < 4; ++i)
        *(float4*)(wb + (r0 + (i << 5)) * 16) = rg[i][0];
    } else {
#pragma unroll
      for (int i = 0; i < 4; ++i) {
        union { bf16x8 v; u16 u[8]; } r;
        r.u[0] = f2bf(rg[i][0].x); r.u[1] = f2bf(rg[i][0].y);
        r.u[2] = f2bf(rg[i][0].z); r.u[3] = f2bf(rg[i][0].w);
        r.u[4] = f2bf(rg[i][1].x); r.u[5] = f2bf(rg[i][1].y);
        r.u[6] = f2bf(rg[i][1].z); r.u[7] = f2bf(rg[i][1].w);
        *(bf16x8*)(wb + (r0 + (i << 5)) * 16) = r.v;
      }
    }
  };
  auto COMPUTE = [&](int buf) {
    const unsigned char* base = smem + buf * BUFSZ;
    bf16x8 af[4], bfr[4];
#pragma unroll
    for (int f = 0; f < 4; ++f) {
      af[f]  = *(const bf16x8*)(base + ardo + f * 256);
      bfr[f] = *(const bf16x8*)(base + brdo + f * 256);
    }
#pragma unroll
    for (int fm = 0; fm < 4; ++fm)
#pragma unroll
      for (int fn = 0; fn < 4; ++fn)
        acc[fm][fn] = __builtin_amdgcn_mfma_f32_16x16x32_bf16(
            af[fm], bfr[fn], acc[fm][fn], 0, 0, 0);
  };

#pragma unroll
  for (int i = 0; i < 4; ++i) {
    rg[i][0] = make_float4(0.f, 0.f, 0.f, 0.f);
    rg[i][1] = make_float4(0.f, 0.f, 0.f, 0.f);
  }
  LOAD(0);
  STORE(0);
  __syncthreads();
  int cur = 0;

  for (int kt = 0; kt < NK; ++kt) {
    if (kt + 1 < NK) LOAD(kt + 1);
    COMPUTE(cur);
    if (kt + 1 < NK) {
      STORE(cur ^ 1);
      __syncthreads();
      cur ^= 1;
    }
  }

  const int orow0 = m0 + wr * 64 + (lk << 2);
  const int ocol0 = n0 + wc * 64 + lr;
#pragma unroll
  for (int fn = 0; fn < 4; ++fn) {
    int col = ocol0 + fn * 16;
    if (col >= N) continue;
    float bv = bias[col];
#pragma unroll
    for (int fm = 0; fm < 4; ++fm)
#pragma unroll
      for (int j = 0; j < 4; ++j) {
        int row = orow0 + fm * 16 + j;
        C[(size_t)row * N + col] = acc[fm][fn][j] + bv;
      }
  }
}

// ---------------------------------------------------------------------------
// k_flashm: MFMA flash attention. qkv bf16 [T,2304] (q|k|v), ctx bf16 [T,768].
// Grid (T/64, H), 256 thr = 4 waves; wave w owns q-rows [q0+16w, q0+16w+16).
// Per KV-tile (64): stage K rows + V^T to LDS (pitch 176B: ~2-way bank =
// free); S = 8 MFMA/wave (A=Q frags in regs, B=K rows); scale+mask; online
// softmax per q-row wave-parallel (shfl_xor 1/2/4/8 in 16-lane groups);
// P->bf16 into per-wave LDS slab (intra-wave only, no barrier); PV = 8
// MFMA/wave (A=P rows, B=V^T rows). C-layout: row=lk*4+j, col=lr+16*fn.
// LDS 33.8KB. qt = gridDim.x-1-blockIdx.x: big tiles launch first.
// ---------------------------------------------------------------------------
__global__ __launch_bounds__(256) void k_flashm(const u16* __restrict__ qkv,
                                                u16* __restrict__ ctx,
                                                int T, float scale) {
  constexpr int PITCH = 176;
  __shared__ alignas(16) unsigned char KT[64 * PITCH];
  __shared__ alignas(16) unsigned char VT[64 * PITCH];
  __shared__ alignas(16) unsigned char PS[4][16 * PITCH];

  const int tid = threadIdx.x;
  const int lane = tid & 63;
  const int w = tid >> 6;
  const int lr = lane & 15, lk = lane >> 4;
  const int qt = gridDim.x - 1 - blockIdx.x;
  const int q0 = qt << 6;
  const int hoff = blockIdx.y << 6;

  // Q fragments (held all kernel): A[m=lr][d=lk*8 + kt*32]
  bf16x8 qf0, qf1;
  {
    const u16* qp = qkv + (size_t)(q0 + w * 16 + lr) * 2304 + hoff + (lk << 3);
    qf0 = *(const bf16x8*)qp;
    qf1 = *(const bf16x8*)(qp + 32);
  }

  float mrow[4] = {-1e30f, -1e30f, -1e30f, -1e30f};
  float lrow[4] = {0.f, 0.f, 0.f, 0.f};
  f32x4 oacc[4] = {};
  unsigned char* pw = PS[w];

  for (int st = 0; st <= qt; ++st) {
    const int s0 = st << 6;
    __syncthreads();  // previous step's K/V readers done
    for (int c = tid; c < 512; c += 256) {
      int row = c >> 3, slot = c & 7;
      const u16* kp = qkv + (size_t)(s0 + row) * 2304 + hoff + 768 + (slot << 3);
      *(bf16x8*)(KT + row * PITCH + (slot << 4)) = *(const bf16x8*)kp;
      union { bf16x8 v; u16 u[8]; } vv;
      vv.v = *(const bf16x8*)(kp + 768);
#pragma unroll
      for (int e = 0; e < 8; ++e)
        *(u16*)(VT + ((slot << 3) + e) * PITCH + (row << 1)) = vv.u[e];
    }
    __syncthreads();

    // S = Q K^T (16q x 64kv per wave)
    f32x4 s[4] = {};
#pragma unroll
    for (int fn = 0; fn < 4; ++fn) {
      bf16x8 kf0 = *(const bf16x8*)(KT + (fn * 16 + lr) * PITCH + (lk << 4));
      bf16x8 kf1 = *(const bf16x8*)(KT + (fn * 16 + lr) * PITCH + (lk << 4) + 64);
      s[fn] = __builtin_amdgcn_mfma_f32_16x16x32_bf16(qf0, kf0, s[fn], 0, 0, 0);
      s[fn] = __builtin_amdgcn_mfma_f32_16x16x32_bf16(qf1, kf1, s[fn], 0, 0, 0);
    }
#pragma unroll
    for (int fn = 0; fn < 4; ++fn) {
      s[fn][0] *= scale; s[fn][1] *= scale;
      s[fn][2] *= scale; s[fn][3] *= scale;
    }

    if (st == qt) {  // causal mask, diagonal tile only
#pragma unroll
      for (int fn = 0; fn < 4; ++fn)
#pragma unroll
        for (int j = 0; j < 4; ++j)
          if (fn * 16 + lr > w * 16 + lk * 4 + j) s[fn][j] = -1e30f;
    }

    // online softmax: rows j (q = lk*4+j), reduce across 16 lr lanes
    float alpha[4];
#pragma unroll
    for (int j = 0; j < 4; ++j) {
      float rmax = fmaxf(fmaxf(s[0][j], s[1][j]), fmaxf(s[2][j], s[3][j]));
      rmax = fmaxf(rmax, __shfl_xor(rmax, 1, 64));
      rmax = fmaxf(rmax, __shfl_xor(rmax, 2, 64));
      rmax = fmaxf(rmax, __shfl_xor(rmax, 4, 64));
      rmax = fmaxf(rmax, __shfl_xor(rmax, 8, 64));
      float mn = fmaxf(mrow[j], rmax);
      alpha[j] = __expf(mrow[j] - mn);
      mrow[j] = mn;
      float rs = 0.f;
#pragma unroll
      for (int fn = 0; fn < 4; ++fn) {
        float p = __expf(s[fn][j] - mn);
        s[fn][j] = p;
        rs += p;
      }
      rs += __shfl_xor(rs, 1, 64);
      rs += __shfl_xor(rs, 2, 64);
      rs += __shfl_xor(rs, 4, 64);
      rs += __shfl_xor(rs, 8, 64);
      lrow[j] = lrow[j] * alpha[j] + rs;
      oacc[0][j] *= alpha[j]; oacc[1][j] *= alpha[j];
      oacc[2][j] *= alpha[j]; oacc[3][j] *= alpha[j];
    }

    // P -> bf16 into this wave's LDS slab (intra-wave RAW, compiler waits)
#pragma unroll
    for (int fn = 0; fn < 4; ++fn)
#pragma unroll
      for (int j = 0; j < 4; ++j)
        *(u16*)(pw + (lk * 4 + j) * PITCH + (fn * 16 + lr) * 2) = f2bf(s[fn][j]);

    // O += P V  (A = P rows [m=lr][kv=lk*8+kt*32], B = V^T rows [d][kv])
#pragma unroll
    for (int kt = 0; kt < 2; ++kt) {
      bf16x8 pf = *(const bf16x8*)(pw + lr * PITCH + (lk << 4) + kt * 64);
#pragma unroll
      for (int fn = 0; fn < 4; ++fn) {
        bf16x8 vf = *(const bf16x8*)(VT + (fn * 16 + lr) * PITCH + (lk << 4) + kt * 64);
        oacc[fn] = __builtin_amdgcn_mfma_f32_16x16x32_bf16(pf, vf, oacc[fn], 0, 0, 0);
      }
    }
  }

  // epilogue: ctx[q][d] bf16, q = q0+16w+lk*4+j, d = hoff+fn*16+lr
#pragma unroll
  for (int j = 0; j < 4; ++j) {
    float inv = 1.0f / lrow[j];
    u16* cp = ctx + (size_t)(q0 + w * 16 + lk * 4 + j) * 768 + hoff;
#pragma unroll
    for (int fn = 0; fn < 4; ++fn)
      cp[fn * 16 + lr] = f2bf(oacc[fn][j] * inv);
  }
}

extern "C" void kernel_launch(void* const* d_in, const int* in_sizes, int n_in,
                              void* d_out, int out_size, void* d_ws, size_t ws_size,
                              hipStream_t stream) {
  const int T = 2048, D = 768, H = 12, L = 4, V = 50257, D4 = 3072;
  const size_t td = (size_t)T * D;

  const int* ids      = (const int*)d_in[0];
  const float* emb    = (const float*)d_in[1];
  const float* lm_bias= (const float*)d_in[2];
  const float* ln1_g  = (const float*)d_in[3];
  const float* ln1_b  = (const float*)d_in[4];
  const float* ln2_g  = (const float*)d_in[5];
  const float* ln2_b  = (const float*)d_in[6];
  const float* Wq     = (const float*)d_in[7];
  const float* bq     = (const float*)d_in[8];
  const float* Wk     = (const float*)d_in[9];
  const float* bk     = (const float*)d_in[10];
  const float* Wv     = (const float*)d_in[11];
  const float* bv     = (const float*)d_in[12];
  const float* Wo     = (const float*)d_in[13];
  const float* bo     = (const float*)d_in[14];
  const float* W1     = (const float*)d_in[15];
  const float* b1     = (const float*)d_in[16];
  const float* W2     = (const float*)d_in[17];
  const float* b2     = (const float*)d_in[18];
  const float* lnf_g  = (const float*)d_in[19];
  const float* lnf_b  = (const float*)d_in[20];
  float* out = (float*)d_out;

  // Scratch:
  //   d_ws: x fp32 [T,768] + xnb bf16 [T,768] (9.4 MB).
  //   d_out front (~190 MB of 412 MB), all dead before the LM-head GEMM
  //   (LMH reads only xnb in ws + emb/lm_bias inputs):
  //     wpool 56.6 | bqkv | qkvb bf16 9.4 | cbb 3.1 | hbb 12.6 |
  //     pqkv 37.7 | pw1 50.3 | po4 25.2  (fp32 split-K partials)
  float* x  = (float*)d_ws;
  u16* xnb  = (u16*)(x + td);

  char* cur = (char*)d_out;
  u16* wpool = (u16*)cur;  cur += (size_t)4 * PER_L * 2;
  float* bqkv = (float*)cur; cur += (size_t)4 * 2304 * 4;
  u16* qkvb = (u16*)cur;     cur += (size_t)T * 2304 * 2;
  u16* cbb = (u16*)cur;      cur += td * 2;
  u16* hbb = (u16*)cur;      cur += (size_t)T * D4 * 2;
  float* pqkv = (float*)cur; cur += (size_t)2 * T * 2304 * 4;
  float* pw1 = (float*)cur;  cur += (size_t)2 * T * D4 * 4;
  float* po4 = (float*)cur;  // 4*T*768*4

  dim3 blk(256);

  k_castw<<<(4 * PER_L) / (256 * 8), blk, 0, stream>>>(Wq, Wk, Wv, Wo, W1, W2, wpool);
  k_castb<<<1, blk, 0, stream>>>(bq, bk, bv, bqkv);

  k_embed<<<T, blk, 0, stream>>>(ids, emb, x, T, D);

  for (int l = 0; l < L; ++l) {
    const u16* wl = wpool + (size_t)l * PER_L;

    k_layernorm<<<T, blk, 0, stream>>>(x, ln1_g + l * D, ln1_b + l * D, xnb, D);

    // QKV: split-K=2 -> fp32 partials -> reduce(+bias) to bf16 qkvb
    k_mm_bf<<<18 * 16 * 2, blk, 0, stream>>>(xnb, wl, nullptr, pqkv,
                                             T, 2304, 768, 3, 2);
    k_red<<<2048, blk, 0, stream>>>(pqkv, 2, bqkv + l * 2304, nullptr,
                                    qkvb, T, 2304, 3);

    dim3 ga(T / 64, H);
    k_flashm<<<ga, blk, 0, stream>>>(qkvb, cbb, T, 0.125f);

    // O-proj: split-K=4 -> reduce(+bias+res) into x
    k_mm_bf<<<6 * 16 * 4, blk, 0, stream>>>(cbb, wl + QKVSZ, nullptr, po4,
                                            T, 768, 768, 3, 4);
    k_red<<<1536, blk, 0, stream>>>(po4, 4, bo + l * D, x, x, T, 768, 1);

    k_layernorm<<<T, blk, 0, stream>>>(x, ln2_g + l * D, ln2_b + l * D, xnb, D);

    // W1: split-K=2 -> reduce(+bias, gelu) to bf16 hbb
    k_mm_bf<<<24 * 16 * 2, blk, 0, stream>>>(xnb, wl + QKVSZ + OSZ, nullptr, pw1,
                                             T, 3072, 768, 3, 2);
    k_red<<<2048, blk, 0, stream>>>(pw1, 2, b1 + l * D4, nullptr,
                                    hbb, T, 3072, 2);

    // W2: split-K=4 -> reduce(+bias+res) into x
    k_mm_bf<<<6 * 16 * 4, blk, 0, stream>>>(hbb, wl + QKVSZ + OSZ + W1SZ, nullptr,
                                            po4, T, 768, 3072, 3, 4);
    k_red<<<1536, blk, 0, stream>>>(po4, 4, b2 + l * D, x, x, T, 768, 1);
  }

  k_layernorm<<<T, blk, 0, stream>>>(x, lnf_g, lnf_b, xnb, D);

  k_mm_lmh<<<((V + 127) / 128) * 16, blk, 0, stream>>>(xnb, emb, lm_bias,
                                                       out, T, V, 768);
}